// Round 1
// baseline (110.244 us; speedup 1.0000x reference)
//
#include <hip/hip_runtime.h>

// out[i][j] = A[i] * B[i][j], N = M = 8192, fp32.
// Pure HBM-streaming op: read B + write out = 512 MiB, A is cache-resident.
// float4 vectorized, grid-stride, 2048 blocks x 256 threads.

#define M_DIM 8192
#define LOG2_M4 11   // M/4 = 2048 float4 per row -> row = i4 >> 11

__global__ __launch_bounds__(256) void scale_rows_f4(
    const float* __restrict__ A,
    const float4* __restrict__ B4,
    float4* __restrict__ O4,
    long n4)
{
    long i = (long)blockIdx.x * blockDim.x + threadIdx.x;
    const long stride = (long)gridDim.x * blockDim.x;
    for (; i < n4; i += stride) {
        const float a = A[i >> LOG2_M4];
        float4 b = B4[i];
        float4 o;
        o.x = a * b.x;
        o.y = a * b.y;
        o.z = a * b.z;
        o.w = a * b.w;
        O4[i] = o;
    }
}

extern "C" void kernel_launch(void* const* d_in, const int* in_sizes, int n_in,
                              void* d_out, int out_size, void* d_ws, size_t ws_size,
                              hipStream_t stream) {
    const float* A = (const float*)d_in[0];          // (8192,)
    const float4* B4 = (const float4*)d_in[1];       // (8192, 8192) as float4
    float4* O4 = (float4*)d_out;

    const long n4 = (long)out_size / 4;              // 16,777,216 float4 elements
    const int block = 256;
    const int grid = 2048;                           // ~8 blocks/CU on 256 CUs, grid-stride

    scale_rows_f4<<<grid, block, 0, stream>>>(A, B4, O4, n4);
}

// Round 2
// 88.743 us; speedup vs baseline: 1.2423x; 1.2423x over previous
//
#include <hip/hip_runtime.h>

// out[i][j] = A[i] * B[i][j], N = M = 8192, fp32.
// HBM-streaming: read B (256 MiB) + write out (256 MiB); A cache-resident.
// float4 loads; NON-TEMPORAL float4 stores (output never re-read) so the
// 256 MiB Infinity Cache stays dedicated to B across graph replays.

#define LOG2_M4 11   // M/4 = 2048 float4 per row -> row = i4 >> 11

typedef float f32x4 __attribute__((ext_vector_type(4)));

__global__ __launch_bounds__(256) void scale_rows_f4_nt(
    const float* __restrict__ A,
    const f32x4* __restrict__ B4,
    f32x4* __restrict__ O4,
    long n4)
{
    long i = (long)blockIdx.x * blockDim.x + threadIdx.x;
    const long stride = (long)gridDim.x * blockDim.x;
    #pragma unroll 4
    for (; i < n4; i += stride) {
        const float a = A[i >> LOG2_M4];
        f32x4 b = B4[i];
        f32x4 o = a * b;
        __builtin_nontemporal_store(o, &O4[i]);
    }
}

extern "C" void kernel_launch(void* const* d_in, const int* in_sizes, int n_in,
                              void* d_out, int out_size, void* d_ws, size_t ws_size,
                              hipStream_t stream) {
    const float* A = (const float*)d_in[0];          // (8192,)
    const f32x4* B4 = (const f32x4*)d_in[1];         // (8192, 8192) as float4
    f32x4* O4 = (f32x4*)d_out;

    const long n4 = (long)out_size / 4;              // 2^24 float4 elements
    const int block = 256;
    const int grid = 2048;                           // full occupancy: 2048*256 = 256 CU * 2048 thr

    scale_rows_f4_nt<<<grid, block, 0, stream>>>(A, B4, O4, n4);
}

// Round 3
// 82.121 us; speedup vs baseline: 1.3425x; 1.0806x over previous
//
#include <hip/hip_runtime.h>

// out[i][j] = A[i] * B[i][j], N = M = 8192, fp32.
// One block per row: A[row] is a wave-uniform scalar (s_load + broadcast).
// Each of 256 threads handles 8 float4s: 8 independent loads batched in
// flight, then 8 non-temporal stores (output never re-read -> keep L3 for B).

typedef float f32x4 __attribute__((ext_vector_type(4)));

#define M4 2048   // float4 per row (M = 8192)

__global__ __launch_bounds__(256) void scale_row_block(
    const float* __restrict__ A,
    const f32x4* __restrict__ B4,
    f32x4* __restrict__ O4)
{
    const int row = blockIdx.x;            // grid = 8192 rows
    const float a = A[row];                // uniform -> scalar load, no per-iter vector load
    const long base = (long)row * M4;
    const int t = threadIdx.x;

    f32x4 b[8];
    #pragma unroll
    for (int k = 0; k < 8; ++k)
        b[k] = B4[base + k * 256 + t];     // 8 loads in flight (deep MLP)

    #pragma unroll
    for (int k = 0; k < 8; ++k)
        __builtin_nontemporal_store(a * b[k], &O4[base + k * 256 + t]);
}

extern "C" void kernel_launch(void* const* d_in, const int* in_sizes, int n_in,
                              void* d_out, int out_size, void* d_ws, size_t ws_size,
                              hipStream_t stream) {
    const float* A = (const float*)d_in[0];      // (8192,)
    const f32x4* B4 = (const f32x4*)d_in[1];     // (8192, 8192) as float4
    f32x4* O4 = (f32x4*)d_out;

    const int N_ROWS = 8192;
    scale_row_block<<<N_ROWS, 256, 0, stream>>>(A, B4, O4);
}